// Round 8
// baseline (2437.505 us; speedup 1.0000x reference)
//
#include <hip/hip_runtime.h>
#include <cstdint>
#include <cstddef>

// Problem constants (match reference)
#define S_LEN 256
#define BB    32
#define EMBD  256
#define HID   256
#define NTAG  10
#define L_TOT (BB*S_LEN)      // 8192 flattened viterbi length
#define NEGV  -10000.0f
#define SOS_I 1
#define EOS_I 2

__device__ __forceinline__ float sigf(float x) { return 1.0f / (1.0f + expf(-x)); }

// ---------------------------------------------------------------------------
// prep_all: fused embedding gather + weight transpose + bias combine.
// blocks [0,8192): E rows; [8192,12288): Wt; 12288: bias.
// ---------------------------------------------------------------------------
__global__ __launch_bounds__(256) void prep_all(
    const int* __restrict__ x, const float* __restrict__ emb,
    const float* __restrict__ Wih_f, const float* __restrict__ Whh_f,
    const float* __restrict__ Wih_b, const float* __restrict__ Whh_b,
    const float* __restrict__ bih_f, const float* __restrict__ bhh_f,
    const float* __restrict__ bih_b, const float* __restrict__ bhh_b,
    float* __restrict__ E, float* __restrict__ Wt, float* __restrict__ bc) {
    const int blk = blockIdx.x;
    const int tid = threadIdx.x;
    if (blk < 8192) {                  // E[t*32+b][m] = emb[x[b][t]][m]
        const int t = blk >> 5, b = blk & 31;
        const int xi = x[b * S_LEN + t];
        E[(size_t)blk * EMBD + tid] = emb[(size_t)xi * EMBD + tid];
    } else if (blk < 8192 + 4096) {    // Wt[d][k][j] (k-major)
        const int idx = blk - 8192;
        const int dk = idx >> 2;       // d*512 + k
        const int d = dk >> 9, k = dk & 511;
        const int j = (idx & 3) * 256 + tid;
        const float* src = (d == 0) ? ((k < 256) ? Wih_f : Whh_f)
                                    : ((k < 256) ? Wih_b : Whh_b);
        Wt[(size_t)dk * 1024 + j] = src[(size_t)j * 256 + (k & 255)];
    } else {                           // bc
        #pragma unroll
        for (int r = 0; r < 8; ++r) {
            const int i = tid + r * 256;
            bc[i] = (i < 1024) ? (bih_f[i] + bhh_f[i]) : (bih_b[i - 1024] + bhh_b[i - 1024]);
        }
    }
}

// ---------------------------------------------------------------------------
// Persistent BiLSTM recurrence — single barrier per step.
// 256 blocks x 1024 thr. group g=blk&15 -> (d=g>>3, bg=g&7: 4 batches);
// member mg=blk>>4 (m-slice of 16). Waves 0-7: e k-slices; 8-15: h k-slices.
// Per step s (pc=s&1, pn=pc^1), after the single __syncthreads:
//   wave0 : post(s) from part[pc] (16x aligned b128) -> h atomic-stores ->
//           vmcnt(0) -> flag(s+1) [earliest signal] -> e-slice0 compute ->
//           stage st_e for s+2.
//   e-waves: compute part_e(s+1) from double-buffered st_e[pn] (staged a
//           full step earlier) -> stage st_e[pc] for s+2.  Entirely overlaps
//           the h-exchange RTT.
//   h-waves: poll own 2 member flags -> per-lane agent-atomic h loads ->
//           per-wave ministage hst[wh] -> uniform b128 reads -> fma.
// part layout [buf][b][gate][m][20]: writes conflict-bounded, post reads are
// 16B-aligned b128 (m*80B + q*16B), 2-way max bank aliasing (free).
// ---------------------------------------------------------------------------
__global__ __launch_bounds__(1024) void lstm_rec(
    const float* __restrict__ E,      // [8192 rows t*32+b][256]
    const float* __restrict__ Wt,     // [2][512 fused k][1024 j]
    const float* __restrict__ bc,     // [2][1024]
    float* __restrict__ hh,           // [2][256 s][32 b][256 m]
    unsigned int* __restrict__ flags) {  // [16 groups][16 members]
    const int blk = blockIdx.x;
    const int g   = blk & 15;
    const int mg  = blk >> 4;
    const int d   = g >> 3;
    const int bg  = g & 7;
    const int tid = threadIdx.x;
    const int wave = __builtin_amdgcn_readfirstlane(tid >> 6);  // 0..15
    const int lane = tid & 63;
    const bool is_h = wave >= 8;
    const int wh = wave & 7;
    const int kb = wave * 32;                // fused-k base (h: 256+wh*32)
    const int jg = (lane >> 4) * 256 + mg * 16 + (lane & 15);

    // persistent weights: w[i] = Wt[d][kb+i][jg]   (32 VGPRs)
    float w[32];
    {
        const float* wsrc = Wt + ((size_t)d * 512 + kb) * 1024 + jg;
        #pragma unroll
        for (int i = 0; i < 32; ++i) w[i] = wsrc[(size_t)i * 1024];
    }

    __shared__ __align__(16) float part[2][4][4][16][20];  // [buf][b][gate][m][wslot+pad]
    __shared__ __align__(16) float st_e[2][4][256];        // dbuf e activations
    __shared__ __align__(16) float hst[8][4][32];          // per-h-wave ministage
    __shared__ float cst[4][16];
    __shared__ float bias[64];
    if (tid < 64) bias[tid] = bc[d * 1024 + (tid >> 4) * 256 + mg * 16 + (tid & 15)];

    const int b_l = wave & 3;                // batch slot this wave stages
    const int so  = (wave >> 2) * 64 + lane; // element offset within a 256 row
    const size_t erow = (size_t)(bg * 4 + b_l) * 256 + so;
    unsigned int* fl = flags + g * 16;

    // ---- prologue: stage st_e[0] (t(0)), st_e[1] (t(1)); compute part[0] ----
    {
        const int t0 = d ? (S_LEN - 1) : 0;
        const int t1 = d ? (S_LEN - 2) : 1;
        st_e[0][b_l][so] = E[(size_t)t0 * 8192 + erow];
        st_e[1][b_l][so] = E[(size_t)t1 * 8192 + erow];
    }
    __syncthreads();
    {
        float acc[4] = {0.f, 0.f, 0.f, 0.f};
        if (!is_h) {
            #pragma unroll 2
            for (int i = 0; i < 8; ++i) {
                #pragma unroll
                for (int b = 0; b < 4; ++b) {
                    const float4 v = *(const float4*)&st_e[0][b][kb + i * 4];
                    acc[b] = fmaf(v.x, w[i * 4 + 0], acc[b]);
                    acc[b] = fmaf(v.y, w[i * 4 + 1], acc[b]);
                    acc[b] = fmaf(v.z, w[i * 4 + 2], acc[b]);
                    acc[b] = fmaf(v.w, w[i * 4 + 3], acc[b]);
                }
            }
        }
        #pragma unroll
        for (int b = 0; b < 4; ++b) part[0][b][lane >> 4][lane & 15][wave] = acc[b];
    }

    #pragma unroll 1
    for (int s = 0; s < S_LEN; ++s) {
        __syncthreads();                       // part[pc] + st_e[pn] sealed
        const int pc = s & 1, pn = pc ^ 1;

        // ---- wave0: post(s) + earliest signal ----
        if (tid < 64) {
            const int bl = tid >> 4, m = tid & 15;
            float vg[4];
            #pragma unroll
            for (int gg = 0; gg < 4; ++gg) {
                const float* pb = &part[pc][bl][gg][m][0];
                const float4 p0 = *(const float4*)(pb + 0);
                const float4 p1 = *(const float4*)(pb + 4);
                const float4 p2 = *(const float4*)(pb + 8);
                const float4 p3 = *(const float4*)(pb + 12);
                vg[gg] = bias[gg * 16 + m]
                       + ((((p0.x + p0.y) + (p0.z + p0.w)) + ((p1.x + p1.y) + (p1.z + p1.w)))
                        + (((p2.x + p2.y) + (p2.z + p2.w)) + ((p3.x + p3.y) + (p3.z + p3.w))));
            }
            const float iv = sigf(vg[0]);
            const float fv = sigf(vg[1]);
            const float gv = tanhf(vg[2]);
            const float ov = sigf(vg[3]);
            float c = (s == 0) ? 0.f : cst[bl][m];
            c = fv * c + iv * gv;
            cst[bl][m] = c;
            const float hv = ov * tanhf(c);
            __hip_atomic_store(
                &hh[(((size_t)d * S_LEN + s) * 32 + (bg * 4 + bl)) * 256 + mg * 16 + m],
                hv, __ATOMIC_RELAXED, __HIP_MEMORY_SCOPE_AGENT);
            if (s < S_LEN - 1) {
                asm volatile("s_waitcnt vmcnt(0)" ::: "memory");  // own stores coherent
                if (tid == 0)
                    __hip_atomic_store(&fl[mg], (unsigned)(s + 1),
                                       __ATOMIC_RELAXED, __HIP_MEMORY_SCOPE_AGENT);
            }
        }

        if (s < S_LEN - 1) {
            float acc[4] = {0.f, 0.f, 0.f, 0.f};
            if (!is_h) {
                // e-part of step s+1 from LDS (staged one step ago)
                #pragma unroll 2
                for (int i = 0; i < 8; ++i) {
                    #pragma unroll
                    for (int b = 0; b < 4; ++b) {
                        const float4 v = *(const float4*)&st_e[pn][b][kb + i * 4];
                        acc[b] = fmaf(v.x, w[i * 4 + 0], acc[b]);
                        acc[b] = fmaf(v.y, w[i * 4 + 1], acc[b]);
                        acc[b] = fmaf(v.z, w[i * 4 + 2], acc[b]);
                        acc[b] = fmaf(v.w, w[i * 4 + 3], acc[b]);
                    }
                }
                // stage e for step s+2 (consumed after the next barrier)
                if (s + 2 < S_LEN) {
                    const int t2 = d ? (S_LEN - 3 - s) : (s + 2);
                    st_e[pc][b_l][so] = E[(size_t)t2 * 8192 + erow];
                }
            } else {
                // poll ONLY this wave's 2 member flags (m in [wh*32, wh*32+32))
                const unsigned tgt = (unsigned)(s + 1);
                while (true) {
                    unsigned v = tgt;
                    if (lane < 2)
                        v = __hip_atomic_load(&fl[wh * 2 + lane], __ATOMIC_RELAXED, __HIP_MEMORY_SCOPE_AGENT);
                    if (__all((int)(v >= tgt))) break;
                }
                asm volatile("" ::: "memory");   // keep h loads below the poll
                const int bl2 = lane >> 4, kk = (lane & 15) * 2;
                const float* hrow = hh + (((size_t)d * S_LEN + s) * 32 + bg * 4 + bl2) * 256
                                    + wh * 32 + kk;
                hst[wh][bl2][kk]     = __hip_atomic_load(hrow,     __ATOMIC_RELAXED, __HIP_MEMORY_SCOPE_AGENT);
                hst[wh][bl2][kk + 1] = __hip_atomic_load(hrow + 1, __ATOMIC_RELAXED, __HIP_MEMORY_SCOPE_AGENT);
                #pragma unroll 2
                for (int i = 0; i < 8; ++i) {
                    #pragma unroll
                    for (int b = 0; b < 4; ++b) {
                        const float4 v = *(const float4*)&hst[wh][b][i * 4];  // uniform
                        acc[b] = fmaf(v.x, w[i * 4 + 0], acc[b]);
                        acc[b] = fmaf(v.y, w[i * 4 + 1], acc[b]);
                        acc[b] = fmaf(v.z, w[i * 4 + 2], acc[b]);
                        acc[b] = fmaf(v.w, w[i * 4 + 3], acc[b]);
                    }
                }
            }
            #pragma unroll
            for (int b = 0; b < 4; ++b) part[pn][b][lane >> 4][lane & 15][wave] = acc[b];
        }
    }
}

// ---------------------------------------------------------------------------
// out[r][tag] = [hf | hb] . Wout[tag] + bout[tag],  r = b*256 + t
// ---------------------------------------------------------------------------
__global__ __launch_bounds__(128) void out_proj(const float* __restrict__ hh,
                                                const float* __restrict__ Wout,
                                                const float* __restrict__ bout,
                                                float* __restrict__ out) {
    const int r = blockIdx.x * blockDim.x + threadIdx.x; // 0..8191
    const int b = r >> 8, t = r & 255;
    const float* hf = hh + (((size_t)0 * S_LEN + t) * 32 + b) * 256;
    const float* hb = hh + (((size_t)1 * S_LEN + (S_LEN - 1 - t)) * 32 + b) * 256;
    float acc[NTAG];
    #pragma unroll
    for (int q = 0; q < NTAG; ++q) acc[q] = bout[q];
    for (int m = 0; m < HID; ++m) {
        const float hv = hf[m];
        #pragma unroll
        for (int q = 0; q < NTAG; ++q) acc[q] = fmaf(hv, Wout[q * 512 + m], acc[q]);
    }
    for (int m = 0; m < HID; ++m) {
        const float hv = hb[m];
        #pragma unroll
        for (int q = 0; q < NTAG; ++q) acc[q] = fmaf(hv, Wout[q * 512 + 256 + m], acc[q]);
    }
    #pragma unroll
    for (int q = 0; q < NTAG; ++q) out[(size_t)r * NTAG + q] = acc[q];
}

// ---------------------------------------------------------------------------
// Viterbi forward + fused backpointers. Sequential chain: add -> max-tree ->
// add -> readlane broadcast (exact reference arithmetic). Argmax (first-max
// cndmask tree) is OFF the serial chain; bp packed 4 steps per dword.
// ---------------------------------------------------------------------------
#define CMB2(va,ia,vb,ib,vo,io) do { const bool _t = (vb) > (va); \
    (vo) = _t ? (vb) : (va); (io) = _t ? (ib) : (ia); } while (0)

__global__ __launch_bounds__(64) void viterbi_fv(const float* __restrict__ feats,
                                                 const float* __restrict__ trans,
                                                 unsigned int* __restrict__ bp4,
                                                 float* __restrict__ score_out,
                                                 int* __restrict__ best_out) {
    const int lane = threadIdx.x;
    float trow[NTAG];
    #pragma unroll
    for (int f = 0; f < NTAG; ++f) trow[f] = (lane < NTAG) ? trans[lane * NTAG + f] : -3.0e38f;
    float fv[NTAG];
    #pragma unroll
    for (int f = 0; f < NTAG; ++f) fv[f] = (f == SOS_I) ? 0.f : NEGV;
    float fq[8];
    #pragma unroll
    for (int q = 0; q < 8; ++q) fq[q] = (lane < NTAG) ? feats[q * NTAG + lane] : 0.f;

    unsigned pk = 0;
    for (int r8 = 0; r8 < L_TOT; r8 += 8) {
        #pragma unroll
        for (int q = 0; q < 8; ++q) {
            const int r = r8 + q;
            float sc[NTAG];
            #pragma unroll
            for (int f = 0; f < NTAG; ++f) sc[f] = fv[f] + trow[f];
            // serial-chain value: max3-shaped tree
            const float m1 = fmaxf(fmaxf(sc[0], sc[1]), sc[2]);
            const float m2 = fmaxf(fmaxf(sc[3], sc[4]), sc[5]);
            const float m3 = fmaxf(fmaxf(sc[6], sc[7]), sc[8]);
            const float mv = fmaxf(fmaxf(fmaxf(m1, m2), m3), sc[9]);
            // off-chain argmax, first-max tie rule (strict > keeps lower idx)
            float vA, vB, vC, vD, vE; int iA, iB, iC, iD, iE;
            CMB2(sc[0], 0, sc[1], 1, vA, iA);
            CMB2(sc[2], 2, sc[3], 3, vB, iB);
            CMB2(sc[4], 4, sc[5], 5, vC, iC);
            CMB2(sc[6], 6, sc[7], 7, vD, iD);
            CMB2(sc[8], 8, sc[9], 9, vE, iE);
            CMB2(vA, iA, vB, iB, vA, iA);
            CMB2(vC, iC, vD, iD, vC, iC);
            CMB2(vA, iA, vC, iC, vA, iA);
            CMB2(vA, iA, vE, iE, vA, iA);
            pk |= (unsigned)iA << ((q & 3) * 8);
            if ((q & 3) == 3) {
                if (lane < NTAG) bp4[(size_t)(r >> 2) * NTAG + lane] = pk;
                pk = 0;
            }
            const float fvnew = mv + fq[q];
            const int rn = r + 8;
            fq[q] = (rn < L_TOT && lane < NTAG) ? feats[(size_t)rn * NTAG + lane] : 0.f;
            #pragma unroll
            for (int f = 0; f < NTAG; ++f)
                fv[f] = __uint_as_float(__builtin_amdgcn_readlane(__float_as_uint(fvnew), f));
        }
    }

    if (lane == 0) {
        float bm = fv[0] + trans[EOS_I * NTAG + 0];
        int ba = 0;
        #pragma unroll
        for (int f = 1; f < NTAG; ++f) {
            const float tv = fv[f] + trans[EOS_I * NTAG + f];
            if (tv > bm) { bm = tv; ba = f; }   // strict > => first-max tie rule
        }
        score_out[0] = bm;
        best_out[0] = ba;
    }
}

// Chunked backtrace (exact function-composition scan over [10]->[10] maps).
// bp packed 4 steps/dword: byte (t&3) of bp4[(t>>2)*NTAG + tag].
__device__ __forceinline__ int bp_at(const unsigned int* bp4, int t, int tag) {
    return (int)((bp4[(size_t)(t >> 2) * NTAG + tag] >> ((t & 3) * 8)) & 0xffu);
}

__global__ __launch_bounds__(1024) void backtrace(const unsigned int* __restrict__ bp4,
                                                  const int* __restrict__ best_in,
                                                  float* __restrict__ path_out) {
    __shared__ unsigned char fc[128 * NTAG];
    __shared__ unsigned char topt[128];
    const int tid = threadIdx.x;
    for (int pe = tid; pe < 128 * NTAG; pe += 1024) {
        const int c = pe / NTAG, e = pe - c * NTAG;
        int cur = e;
        for (int i = 63; i >= 0; --i) cur = bp_at(bp4, c * 64 + i, cur);
        fc[c * NTAG + e] = (unsigned char)cur;
    }
    __syncthreads();
    if (tid == 0) {
        int carry = best_in[0];
        for (int c = 127; c >= 0; --c) {
            topt[c] = (unsigned char)carry;
            carry = fc[c * NTAG + carry];
        }
    }
    __syncthreads();
    for (int c = tid; c < 128; c += 1024) {
        int cur = topt[c];
        for (int i = 63; i >= 0; --i) {
            const int t = c * 64 + i;
            path_out[t] = (float)cur;
            cur = bp_at(bp4, t, cur);
        }
    }
}

// ---------------------------------------------------------------------------
extern "C" void kernel_launch(void* const* d_in, const int* in_sizes, int n_in,
                              void* d_out, int out_size, void* d_ws, size_t ws_size,
                              hipStream_t stream) {
    const int*   x     = (const int*)d_in[0];
    const float* emb   = (const float*)d_in[3];
    const float* Wih_f = (const float*)d_in[4];
    const float* Whh_f = (const float*)d_in[5];
    const float* bih_f = (const float*)d_in[6];
    const float* bhh_f = (const float*)d_in[7];
    const float* Wih_b = (const float*)d_in[8];
    const float* Whh_b = (const float*)d_in[9];
    const float* bih_b = (const float*)d_in[10];
    const float* bhh_b = (const float*)d_in[11];
    const float* Wout  = (const float*)d_in[12];
    const float* bout  = (const float*)d_in[13];
    const float* trans = (const float*)d_in[14];

    char* ws = (char*)d_ws;
    size_t off = 0;
    auto alloc = [&](size_t bytes) { void* p = ws + off; off += (bytes + 255) & ~(size_t)255; return p; };
    unsigned*      flags = (unsigned*)alloc(16 * 16 * 4);                 // 1 KB
    int*           best  = (int*)alloc(256);
    float*         E     = (float*)alloc((size_t)L_TOT * EMBD * 4);       // 8.4 MB
    float*         Wt    = (float*)alloc((size_t)2 * 512 * 1024 * 4);     // 4 MB
    float*         bc    = (float*)alloc(2048 * 4);
    float*         hh    = (float*)alloc((size_t)2 * S_LEN * BB * HID * 4); // 16.8 MB
    unsigned*      bp4   = (unsigned*)alloc((size_t)(L_TOT / 4) * NTAG * 4); // 80 KB

    float* out   = (float*)d_out;                  // [0 .. 81920)
    float* score = out + (size_t)L_TOT * NTAG;     // [81920]
    float* path  = score + 1;                      // [81921 .. 90113)

    (void)hipMemsetAsync(flags, 0, 16 * 16 * 4, stream);  // flags must start at 0 every call
    hipLaunchKernelGGL(prep_all,  dim3(12289), dim3(256), 0, stream,
                       x, emb, Wih_f, Whh_f, Wih_b, Whh_b,
                       bih_f, bhh_f, bih_b, bhh_b, E, Wt, bc);
    hipLaunchKernelGGL(lstm_rec,  dim3(256),   dim3(1024), 0, stream, E, Wt, bc, hh, flags);
    hipLaunchKernelGGL(out_proj,  dim3(L_TOT / 128), dim3(128), 0, stream, hh, Wout, bout, out);
    hipLaunchKernelGGL(viterbi_fv, dim3(1),    dim3(64),   0, stream, out, trans, bp4, score, best);
    hipLaunchKernelGGL(backtrace, dim3(1),     dim3(1024), 0, stream, bp4, best, path);
}

// Round 9
// 1518.167 us; speedup vs baseline: 1.6056x; 1.6056x over previous
//
#include <hip/hip_runtime.h>
#include <cstdint>
#include <cstddef>

// Problem constants (match reference)
#define S_LEN 256
#define BB    32
#define EMBD  256
#define HID   256
#define NTAG  10
#define L_TOT (BB*S_LEN)      // 8192 flattened viterbi length
#define NEGV  -10000.0f
#define SOS_I 1
#define EOS_I 2

__device__ __forceinline__ float sigf(float x) { return 1.0f / (1.0f + expf(-x)); }

// ---------------------------------------------------------------------------
// prep_all: fused embedding gather + weight transpose + bias combine.
// blocks [0,8192): E rows; [8192,12288): Wt; 12288: bias.
// ---------------------------------------------------------------------------
__global__ __launch_bounds__(256) void prep_all(
    const int* __restrict__ x, const float* __restrict__ emb,
    const float* __restrict__ Wih_f, const float* __restrict__ Whh_f,
    const float* __restrict__ Wih_b, const float* __restrict__ Whh_b,
    const float* __restrict__ bih_f, const float* __restrict__ bhh_f,
    const float* __restrict__ bih_b, const float* __restrict__ bhh_b,
    float* __restrict__ E, float* __restrict__ Wt, float* __restrict__ bc) {
    const int blk = blockIdx.x;
    const int tid = threadIdx.x;
    if (blk < 8192) {                  // E[t*32+b][m] = emb[x[b][t]][m]
        const int t = blk >> 5, b = blk & 31;
        const int xi = x[b * S_LEN + t];
        E[(size_t)blk * EMBD + tid] = emb[(size_t)xi * EMBD + tid];
    } else if (blk < 8192 + 4096) {    // Wt[d][k][j] (k-major)
        const int idx = blk - 8192;
        const int dk = idx >> 2;       // d*512 + k
        const int d = dk >> 9, k = dk & 511;
        const int j = (idx & 3) * 256 + tid;
        const float* src = (d == 0) ? ((k < 256) ? Wih_f : Whh_f)
                                    : ((k < 256) ? Wih_b : Whh_b);
        Wt[(size_t)dk * 1024 + j] = src[(size_t)j * 256 + (k & 255)];
    } else {                           // bc
        #pragma unroll
        for (int r = 0; r < 8; ++r) {
            const int i = tid + r * 256;
            bc[i] = (i < 1024) ? (bih_f[i] + bhh_f[i]) : (bih_b[i - 1024] + bhh_b[i - 1024]);
        }
    }
}

// ---------------------------------------------------------------------------
// Persistent BiLSTM recurrence — single barrier per step, ONE-RTT exchange.
// 256 blocks x 1024 thr. group g=blk&15 -> (d=g>>3, bg=g&7: 4 batches);
// member mg=blk>>4 (m-slice of 16). Waves 0-7: e k-slices; 8-15: h k-slices.
// h exchange via SELF-VALIDATING u64 mailboxes: producer stores {tag=s+1
// (hi32), h bits (lo32)} relaxed/agent into mb[g][(s+1)&1][b][m]; consumers
// poll their 2 payload words directly (data IS the flag) -> no vmcnt, no
// separate flag, no second load: exposed latency = store flight + poll/2.
// Parity double-buffer is overrun-safe: slot rewritten only 2 steps later,
// and the group lockstep (every block consumes every member each step)
// guarantees consumption first. 256KB memset/launch kills cross-replay tags.
// ---------------------------------------------------------------------------
__global__ __launch_bounds__(1024) void lstm_rec(
    const float* __restrict__ E,      // [8192 rows t*32+b][256]
    const float* __restrict__ Wt,     // [2][512 fused k][1024 j]
    const float* __restrict__ bc,     // [2][1024]
    float* __restrict__ hh,           // [2][256 s][32 b][256 m] (for out_proj)
    unsigned long long* __restrict__ mb) {  // [16 g][2 par][4 b][256 m]
    const int blk = blockIdx.x;
    const int g   = blk & 15;
    const int mg  = blk >> 4;
    const int d   = g >> 3;
    const int bg  = g & 7;
    const int tid = threadIdx.x;
    const int wave = __builtin_amdgcn_readfirstlane(tid >> 6);  // 0..15
    const int lane = tid & 63;
    const bool is_h = wave >= 8;
    const int wh = wave & 7;
    const int kb = wave * 32;                // fused-k base (h: 256+wh*32)
    const int jg = (lane >> 4) * 256 + mg * 16 + (lane & 15);

    // persistent weights: w[i] = Wt[d][kb+i][jg]   (32 VGPRs)
    float w[32];
    {
        const float* wsrc = Wt + ((size_t)d * 512 + kb) * 1024 + jg;
        #pragma unroll
        for (int i = 0; i < 32; ++i) w[i] = wsrc[(size_t)i * 1024];
    }

    __shared__ __align__(16) float part[2][4][4][16][20];  // [buf][b][gate][m][wslot+pad]
    __shared__ __align__(16) float st_e[2][4][256];        // dbuf e activations
    __shared__ __align__(16) float hst[8][4][32];          // per-h-wave ministage
    __shared__ float cst[4][16];
    __shared__ float bias[64];
    if (tid < 64) bias[tid] = bc[d * 1024 + (tid >> 4) * 256 + mg * 16 + (tid & 15)];

    const int b_l = wave & 3;                // batch slot this wave stages
    const int so  = (wave >> 2) * 64 + lane; // element offset within a 256 row
    const size_t erow = (size_t)(bg * 4 + b_l) * 256 + so;

    // ---- prologue: stage st_e[0] (t(0)), st_e[1] (t(1)); compute part[0] ----
    {
        const int t0 = d ? (S_LEN - 1) : 0;
        const int t1 = d ? (S_LEN - 2) : 1;
        st_e[0][b_l][so] = E[(size_t)t0 * 8192 + erow];
        st_e[1][b_l][so] = E[(size_t)t1 * 8192 + erow];
    }
    __syncthreads();
    {
        float acc[4] = {0.f, 0.f, 0.f, 0.f};
        if (!is_h) {
            #pragma unroll 2
            for (int i = 0; i < 8; ++i) {
                #pragma unroll
                for (int b = 0; b < 4; ++b) {
                    const float4 v = *(const float4*)&st_e[0][b][kb + i * 4];
                    acc[b] = fmaf(v.x, w[i * 4 + 0], acc[b]);
                    acc[b] = fmaf(v.y, w[i * 4 + 1], acc[b]);
                    acc[b] = fmaf(v.z, w[i * 4 + 2], acc[b]);
                    acc[b] = fmaf(v.w, w[i * 4 + 3], acc[b]);
                }
            }
        }
        #pragma unroll
        for (int b = 0; b < 4; ++b) part[0][b][lane >> 4][lane & 15][wave] = acc[b];
    }

    #pragma unroll 1
    for (int s = 0; s < S_LEN; ++s) {
        __syncthreads();                       // part[pc] + st_e[pn] sealed
        const int pc = s & 1, pn = pc ^ 1;

        // ---- wave0: post(s); mailbox store is the earliest possible signal ----
        if (tid < 64) {
            const int bl = tid >> 4, m = tid & 15;
            float vg[4];
            #pragma unroll
            for (int gg = 0; gg < 4; ++gg) {
                const float* pb = &part[pc][bl][gg][m][0];
                const float4 p0 = *(const float4*)(pb + 0);
                const float4 p1 = *(const float4*)(pb + 4);
                const float4 p2 = *(const float4*)(pb + 8);
                const float4 p3 = *(const float4*)(pb + 12);
                vg[gg] = bias[gg * 16 + m]
                       + ((((p0.x + p0.y) + (p0.z + p0.w)) + ((p1.x + p1.y) + (p1.z + p1.w)))
                        + (((p2.x + p2.y) + (p2.z + p2.w)) + ((p3.x + p3.y) + (p3.z + p3.w))));
            }
            const float iv = sigf(vg[0]);
            const float fv = sigf(vg[1]);
            const float gv = tanhf(vg[2]);
            const float ov = sigf(vg[3]);
            float c = (s == 0) ? 0.f : cst[bl][m];
            c = fv * c + iv * gv;
            cst[bl][m] = c;
            const float hv = ov * tanhf(c);
            if (s < S_LEN - 1) {
                // self-validating payload: {tag = s+1, h bits}
                const unsigned long long pv =
                    ((unsigned long long)(unsigned)(s + 1) << 32) |
                    (unsigned long long)__float_as_uint(hv);
                __hip_atomic_store(
                    &mb[(((size_t)g * 2 + ((s + 1) & 1)) * 4 + bl) * 256 + mg * 16 + m],
                    pv, __ATOMIC_RELAXED, __HIP_MEMORY_SCOPE_AGENT);
            }
            // plain store for out_proj (off critical path)
            hh[(((size_t)d * S_LEN + s) * 32 + (bg * 4 + bl)) * 256 + mg * 16 + m] = hv;
        }

        if (s < S_LEN - 1) {
            float acc[4] = {0.f, 0.f, 0.f, 0.f};
            if (!is_h) {
                // e-part of step s+1 from LDS (staged one step ago)
                #pragma unroll 2
                for (int i = 0; i < 8; ++i) {
                    #pragma unroll
                    for (int b = 0; b < 4; ++b) {
                        const float4 v = *(const float4*)&st_e[pn][b][kb + i * 4];
                        acc[b] = fmaf(v.x, w[i * 4 + 0], acc[b]);
                        acc[b] = fmaf(v.y, w[i * 4 + 1], acc[b]);
                        acc[b] = fmaf(v.z, w[i * 4 + 2], acc[b]);
                        acc[b] = fmaf(v.w, w[i * 4 + 3], acc[b]);
                    }
                }
                // stage e for step s+2 (consumed after the next barrier)
                if (s + 2 < S_LEN) {
                    const int t2 = d ? (S_LEN - 3 - s) : (s + 2);
                    st_e[pc][b_l][so] = E[(size_t)t2 * 8192 + erow];
                }
            } else {
                // poll own 2 payload words; tag match == data ready
                const unsigned tgt = (unsigned)(s + 1);
                const int bl2 = lane >> 4, kk = (lane & 15) * 2;
                const size_t base = (((size_t)g * 2 + ((s + 1) & 1)) * 4 + bl2) * 256
                                    + wh * 32 + kk;
                unsigned long long a, b;
                while (true) {
                    a = __hip_atomic_load(&mb[base],     __ATOMIC_RELAXED, __HIP_MEMORY_SCOPE_AGENT);
                    b = __hip_atomic_load(&mb[base + 1], __ATOMIC_RELAXED, __HIP_MEMORY_SCOPE_AGENT);
                    const bool ok = ((unsigned)(a >> 32) == tgt) && ((unsigned)(b >> 32) == tgt);
                    if (__all((int)ok)) break;
                }
                hst[wh][bl2][kk]     = __uint_as_float((unsigned)a);
                hst[wh][bl2][kk + 1] = __uint_as_float((unsigned)b);
                #pragma unroll 2
                for (int i = 0; i < 8; ++i) {
                    #pragma unroll
                    for (int b4 = 0; b4 < 4; ++b4) {
                        const float4 v = *(const float4*)&hst[wh][b4][i * 4];  // uniform
                        acc[b4] = fmaf(v.x, w[i * 4 + 0], acc[b4]);
                        acc[b4] = fmaf(v.y, w[i * 4 + 1], acc[b4]);
                        acc[b4] = fmaf(v.z, w[i * 4 + 2], acc[b4]);
                        acc[b4] = fmaf(v.w, w[i * 4 + 3], acc[b4]);
                    }
                }
            }
            #pragma unroll
            for (int b = 0; b < 4; ++b) part[pn][b][lane >> 4][lane & 15][wave] = acc[b];
        }
    }
}

// ---------------------------------------------------------------------------
// out[r][tag] = [hf | hb] . Wout[tag] + bout[tag],  r = b*256 + t
// ---------------------------------------------------------------------------
__global__ __launch_bounds__(128) void out_proj(const float* __restrict__ hh,
                                                const float* __restrict__ Wout,
                                                const float* __restrict__ bout,
                                                float* __restrict__ out) {
    const int r = blockIdx.x * blockDim.x + threadIdx.x; // 0..8191
    const int b = r >> 8, t = r & 255;
    const float* hf = hh + (((size_t)0 * S_LEN + t) * 32 + b) * 256;
    const float* hb = hh + (((size_t)1 * S_LEN + (S_LEN - 1 - t)) * 32 + b) * 256;
    float acc[NTAG];
    #pragma unroll
    for (int q = 0; q < NTAG; ++q) acc[q] = bout[q];
    for (int m = 0; m < HID; ++m) {
        const float hv = hf[m];
        #pragma unroll
        for (int q = 0; q < NTAG; ++q) acc[q] = fmaf(hv, Wout[q * 512 + m], acc[q]);
    }
    for (int m = 0; m < HID; ++m) {
        const float hv = hb[m];
        #pragma unroll
        for (int q = 0; q < NTAG; ++q) acc[q] = fmaf(hv, Wout[q * 512 + 256 + m], acc[q]);
    }
    #pragma unroll
    for (int q = 0; q < NTAG; ++q) out[(size_t)r * NTAG + q] = acc[q];
}

// ---------------------------------------------------------------------------
// Viterbi forward values ONLY (exact reference arithmetic per step).
// Lanes 0..9 = 'to'. readlane->SGPR broadcast; max3-shaped tree; feats
// prefetched 8 deep. Stores fv history for the parallel backpointer kernel.
// ---------------------------------------------------------------------------
__global__ __launch_bounds__(64) void viterbi_fv(const float* __restrict__ feats,
                                                 const float* __restrict__ trans,
                                                 float* __restrict__ fvh,
                                                 float* __restrict__ score_out,
                                                 int* __restrict__ best_out) {
    const int lane = threadIdx.x;
    float trow[NTAG];
    #pragma unroll
    for (int f = 0; f < NTAG; ++f) trow[f] = (lane < NTAG) ? trans[lane * NTAG + f] : -3.0e38f;
    float fv[NTAG];
    #pragma unroll
    for (int f = 0; f < NTAG; ++f) fv[f] = (f == SOS_I) ? 0.f : NEGV;
    float fq[8];
    #pragma unroll
    for (int q = 0; q < 8; ++q) fq[q] = (lane < NTAG) ? feats[q * NTAG + lane] : 0.f;

    for (int r8 = 0; r8 < L_TOT; r8 += 8) {
        #pragma unroll
        for (int q = 0; q < 8; ++q) {
            const int r = r8 + q;
            float sc[NTAG];
            #pragma unroll
            for (int f = 0; f < NTAG; ++f) sc[f] = fv[f] + trow[f];
            // max3-shaped tree (4 v_max3 + 1 v_max, depth 3)
            const float m1 = fmaxf(fmaxf(sc[0], sc[1]), sc[2]);
            const float m2 = fmaxf(fmaxf(sc[3], sc[4]), sc[5]);
            const float m3 = fmaxf(fmaxf(sc[6], sc[7]), sc[8]);
            const float mv = fmaxf(fmaxf(fmaxf(m1, m2), m3), sc[9]);
            const float fvnew = mv + fq[q];
            if (lane < NTAG) fvh[(size_t)r * NTAG + lane] = fvnew;
            const int rn = r + 8;
            fq[q] = (rn < L_TOT && lane < NTAG) ? feats[(size_t)rn * NTAG + lane] : 0.f;
            #pragma unroll
            for (int f = 0; f < NTAG; ++f)
                fv[f] = __uint_as_float(__builtin_amdgcn_readlane(__float_as_uint(fvnew), f));
        }
    }

    if (lane == 0) {
        float bm = fv[0] + trans[EOS_I * NTAG + 0];
        int ba = 0;
        #pragma unroll
        for (int f = 1; f < NTAG; ++f) {
            const float tv = fv[f] + trans[EOS_I * NTAG + f];
            if (tv > bm) { bm = tv; ba = f; }   // strict > => first-max tie rule
        }
        score_out[0] = bm;
        best_out[0] = ba;
    }
}

// Backpointers, fully parallel, packed 4 steps/dword:
// thread (quad, to): bp4[quad*NTAG+to] bytes q = argmax_f(fv[r-1][f]+T[to][f])
__global__ __launch_bounds__(256) void viterbi_bp(const float* __restrict__ fvh,
                                                  const float* __restrict__ trans,
                                                  unsigned int* __restrict__ bp4) {
    const int idx = blockIdx.x * blockDim.x + threadIdx.x;
    if (idx >= (L_TOT / 4) * NTAG) return;
    const int quad = idx / NTAG, to = idx - quad * NTAG;
    float trow[NTAG];
    #pragma unroll
    for (int f = 0; f < NTAG; ++f) trow[f] = trans[to * NTAG + f];
    unsigned pk = 0;
    #pragma unroll
    for (int q = 0; q < 4; ++q) {
        const int r = quad * 4 + q;
        float best = 0.f;
        int arg = 0;
        #pragma unroll
        for (int f = 0; f < NTAG; ++f) {
            const float fp = r ? fvh[(size_t)(r - 1) * NTAG + f]
                               : ((f == SOS_I) ? 0.f : NEGV);
            const float s = fp + trow[f];
            if (f == 0) best = s;
            else if (s > best) { best = s; arg = f; }  // strict > => first-max
        }
        pk |= (unsigned)arg << (q * 8);
    }
    bp4[(size_t)quad * NTAG + to] = pk;
}

// Chunked backtrace (exact function-composition scan over [10]->[10] maps).
// bp packed 4 steps/dword: byte (t&3) of bp4[(t>>2)*NTAG + tag].
__device__ __forceinline__ int bp_at(const unsigned int* bp4, int t, int tag) {
    return (int)((bp4[(size_t)(t >> 2) * NTAG + tag] >> ((t & 3) * 8)) & 0xffu);
}

__global__ __launch_bounds__(1024) void backtrace(const unsigned int* __restrict__ bp4,
                                                  const int* __restrict__ best_in,
                                                  float* __restrict__ path_out) {
    __shared__ unsigned char fc[128 * NTAG];
    __shared__ unsigned char topt[128];
    const int tid = threadIdx.x;
    for (int pe = tid; pe < 128 * NTAG; pe += 1024) {
        const int c = pe / NTAG, e = pe - c * NTAG;
        int cur = e;
        for (int i = 63; i >= 0; --i) cur = bp_at(bp4, c * 64 + i, cur);
        fc[c * NTAG + e] = (unsigned char)cur;
    }
    __syncthreads();
    if (tid == 0) {
        int carry = best_in[0];
        for (int c = 127; c >= 0; --c) {
            topt[c] = (unsigned char)carry;
            carry = fc[c * NTAG + carry];
        }
    }
    __syncthreads();
    for (int c = tid; c < 128; c += 1024) {
        int cur = topt[c];
        for (int i = 63; i >= 0; --i) {
            const int t = c * 64 + i;
            path_out[t] = (float)cur;
            cur = bp_at(bp4, t, cur);
        }
    }
}

// ---------------------------------------------------------------------------
extern "C" void kernel_launch(void* const* d_in, const int* in_sizes, int n_in,
                              void* d_out, int out_size, void* d_ws, size_t ws_size,
                              hipStream_t stream) {
    const int*   x     = (const int*)d_in[0];
    const float* emb   = (const float*)d_in[3];
    const float* Wih_f = (const float*)d_in[4];
    const float* Whh_f = (const float*)d_in[5];
    const float* bih_f = (const float*)d_in[6];
    const float* bhh_f = (const float*)d_in[7];
    const float* Wih_b = (const float*)d_in[8];
    const float* Whh_b = (const float*)d_in[9];
    const float* bih_b = (const float*)d_in[10];
    const float* bhh_b = (const float*)d_in[11];
    const float* Wout  = (const float*)d_in[12];
    const float* bout  = (const float*)d_in[13];
    const float* trans = (const float*)d_in[14];

    char* ws = (char*)d_ws;
    size_t off = 0;
    auto alloc = [&](size_t bytes) { void* p = ws + off; off += (bytes + 255) & ~(size_t)255; return p; };
    const size_t MB_BYTES = (size_t)16 * 2 * 4 * 256 * 8;                 // 256 KB
    unsigned long long* mb = (unsigned long long*)alloc(MB_BYTES);
    int*           best  = (int*)alloc(256);
    float*         E     = (float*)alloc((size_t)L_TOT * EMBD * 4);       // 8.4 MB
    float*         Wt    = (float*)alloc((size_t)2 * 512 * 1024 * 4);     // 4 MB
    float*         bc    = (float*)alloc(2048 * 4);
    float*         hh    = (float*)alloc((size_t)2 * S_LEN * BB * HID * 4); // 16.8 MB
    float*         fvh   = (float*)alloc((size_t)L_TOT * NTAG * 4);       // 328 KB
    unsigned*      bp4   = (unsigned*)alloc((size_t)(L_TOT / 4) * NTAG * 4); // 80 KB

    float* out   = (float*)d_out;                  // [0 .. 81920)
    float* score = out + (size_t)L_TOT * NTAG;     // [81920]
    float* path  = score + 1;                      // [81921 .. 90113)

    (void)hipMemsetAsync(mb, 0, MB_BYTES, stream);  // kill cross-replay stale tags
    hipLaunchKernelGGL(prep_all,  dim3(12289), dim3(256), 0, stream,
                       x, emb, Wih_f, Whh_f, Wih_b, Whh_b,
                       bih_f, bhh_f, bih_b, bhh_b, E, Wt, bc);
    hipLaunchKernelGGL(lstm_rec,  dim3(256),   dim3(1024), 0, stream, E, Wt, bc, hh, mb);
    hipLaunchKernelGGL(out_proj,  dim3(L_TOT / 128), dim3(128), 0, stream, hh, Wout, bout, out);
    hipLaunchKernelGGL(viterbi_fv, dim3(1),    dim3(64),   0, stream, out, trans, fvh, score, best);
    hipLaunchKernelGGL(viterbi_bp, dim3(((L_TOT / 4) * NTAG + 255) / 256), dim3(256), 0, stream,
                       fvh, trans, bp4);
    hipLaunchKernelGGL(backtrace, dim3(1),     dim3(1024), 0, stream, bp4, best, path);
}